// Round 5
// baseline (605.287 us; speedup 1.0000x reference)
//
#include <hip/hip_runtime.h>
#include <hip/hip_bf16.h>

// Problem constants (GATLayer): B=8, C=2048, IN=OUT=128, H=4, D=32
constexpr int B_  = 8;
constexpr int C_  = 2048;
constexpr int IND = 128;
constexpr int H_  = 4;
constexpr int D_  = 32;
constexpr int M_  = B_ * C_;          // 16384 tokens
constexpr float QSCALE = 0.17677669529663687f;   // 1/sqrt(32)
constexpr float L2E    = 1.4426950408889634f;
constexpr float QL2    = QSCALE * L2E;           // folded: exp2 needs no mul

// Split-K: global (memory) x intra-block (occupancy). ws_size is < 90 MB
// (R4 overflow lesson) -> keep global split at 4 (55.6 MB total footprint)
// and get the extra 2x wave parallelism by splitting K inside the block
// with an LDS reduction.
constexpr int KSPLIT = 4;             // global split (Opart footprint)
constexpr int KPG = C_ / KSPLIT;      // 512 keys per (block, kz)
constexpr int KPW = KPG / 2;          // 256 keys per wave (intra split 2)

typedef __attribute__((ext_vector_type(8))) short short8;
typedef __attribute__((ext_vector_type(4))) short s4t;
typedef __attribute__((ext_vector_type(4))) float f4t;
typedef __attribute__((ext_vector_type(4))) unsigned short us4;
typedef __attribute__((ext_vector_type(2))) unsigned short us2;

// Device pass has this builtin; host pass doesn't advertise it via
// __has_builtin, so give the host a dummy (never executed).
#if __has_builtin(__builtin_amdgcn_mfma_f32_16x16x16bf16_1k)
#define MFMA16(a, b, c) __builtin_amdgcn_mfma_f32_16x16x16bf16_1k(a, b, c, 0, 0, 0)
#else
#define MFMA16(a, b, c) (c)   // host-pass placeholder
#endif

__device__ __forceinline__ unsigned short f2bf(float f) {
    union { float f; unsigned u; } v; v.f = f;
    unsigned u = v.u + 0x7fffu + ((v.u >> 16) & 1u);   // RNE
    return (unsigned short)(u >> 16);
}

// Pack 4 floats -> 4 bf16 (RNE). Uses v_cvt_pk_bf16_f32 when available
// (device pass on gfx950); falls back to manual RNE otherwise (host pass).
__device__ __forceinline__ s4t pack4_bf16(float p0, float p1, float p2, float p3) {
#if __has_builtin(__builtin_amdgcn_cvt_pk_bf16_f32)
    auto a = __builtin_amdgcn_cvt_pk_bf16_f32(p0, p1);
    auto b = __builtin_amdgcn_cvt_pk_bf16_f32(p2, p3);
    unsigned u[2];
    __builtin_memcpy(&u[0], &a, 4);
    __builtin_memcpy(&u[1], &b, 4);
    s4t pp;
    __builtin_memcpy(&pp, u, 8);
    return pp;
#else
    s4t pp;
    pp[0] = (short)f2bf(p0); pp[1] = (short)f2bf(p1);
    pp[2] = (short)f2bf(p2); pp[3] = (short)f2bf(p3);
    return pp;
#endif
}

// ---------------------------------------------------------------------------
// K1: fused QKV projection (fp32 compute, bf16 outputs).
// 16 rows/block -> 1024 blocks (4/CU); thread tile 2x4.
// Qb scaled by (1/sqrt(D))*log2(e).  Vt is V transposed: Vt[b][d(128)][c].
__global__ __launch_bounds__(256) void qkv_proj_kernel(
    const float* __restrict__ x,
    const float* __restrict__ Wq, const float* __restrict__ Wk,
    const float* __restrict__ Wv,
    unsigned short* __restrict__ Qb, unsigned short* __restrict__ Kb,
    unsigned short* __restrict__ Vt)
{
    __shared__ float xs[16][IND];   // 8 KB
    const int t = threadIdx.x;
    const size_t row0 = (size_t)blockIdx.x * 16;

    const float4* xsrc = (const float4*)(x + row0 * IND);
    float4* xd = (float4*)&xs[0][0];
#pragma unroll
    for (int i = 0; i < 2; ++i) xd[t + i * 256] = xsrc[t + i * 256];
    __syncthreads();

    const int rg = t >> 5, cg = t & 31;
    const int r0 = rg * 2, c0 = cg * 4;
    const int b  = (int)(row0 >> 11);
    const int cb = (int)(row0 & 2047);

#pragma unroll
    for (int w = 0; w < 3; ++w) {
        const float* __restrict__ W = (w == 0) ? Wq : (w == 1) ? Wk : Wv;
        float acc[2][4] = {};
#pragma unroll 4
        for (int k = 0; k < IND; ++k) {
            const float4 wv = *(const float4*)(W + k * IND + c0);
#pragma unroll
            for (int i = 0; i < 2; ++i) {
                const float xr = xs[r0 + i][k];
                acc[i][0] += xr * wv.x;
                acc[i][1] += xr * wv.y;
                acc[i][2] += xr * wv.z;
                acc[i][3] += xr * wv.w;
            }
        }
        if (w == 2) {
            // transposed store: Vt[(b*128 + d)*C + c], 2 consecutive tokens
#pragma unroll
            for (int jj = 0; jj < 4; ++jj) {
                us2 v;
                v[0] = f2bf(acc[0][jj]);
                v[1] = f2bf(acc[1][jj]);
                *(us2*)(Vt + ((size_t)(b * IND + c0 + jj)) * C_ + cb + r0) = v;
            }
        } else {
            const float sc = (w == 0) ? QL2 : 1.0f;
            unsigned short* O = (w == 0) ? Qb : Kb;
#pragma unroll
            for (int i = 0; i < 2; ++i) {
                us4 v;
#pragma unroll
                for (int j = 0; j < 4; ++j) v[j] = f2bf(acc[i][j] * sc);
                *(us4*)(O + (row0 + r0 + i) * IND + c0) = v;
            }
        }
    }
}

// ---------------------------------------------------------------------------
// K2: MFMA flash attention. Scores computed TRANSPOSED so the probability
// tile lands directly in the 16x16x16 PV A-fragment layout.
// Block = 256 threads = 4 waves = 2 q-subtiles x 2 k-halves; the half=1
// waves reduce into half=0 via LDS.  Grid = 64 x 8 x 4 = 2048 blocks ->
// 8192 waves -> 8 waves/SIMD (VGPR<=64 via launch_bounds).
__global__ __launch_bounds__(256, 8) void attn_kernel(
    const unsigned short* __restrict__ Qb, const unsigned short* __restrict__ Kb,
    const unsigned short* __restrict__ Vt, const float* __restrict__ adj,
    float* __restrict__ Opart, float* __restrict__ lpart)
{
    __shared__ float redO[2][16][128];   // 16 KB: [subtile][q][d]
    __shared__ float redL[2][64];        // [subtile][h*16+q]

    const int t    = threadIdx.x;
    const int w    = t >> 6;
    const int s    = w & 1;              // q-subtile
    const int half = w >> 1;             // k-half
    const int l    = t & 63;
    const int lo   = l & 15, hi = l >> 4;
    const int b  = blockIdx.y;
    const int kz = blockIdx.z;
    const int q0 = blockIdx.x * 32;
    const int qs = q0 + s * 16 + lo;     // this lane's q row (0..2047)
    const int k0base = kz * KPG + half * KPW;

    // Q fragments (B-operand of St MFMA): lane holds Q[qs][h*32 + hi*8 .. +8]
    short8 qf[4];
#pragma unroll
    for (int h = 0; h < 4; ++h)
        qf[h] = *(const short8*)(Qb + ((size_t)(b * C_) + qs) * IND + h * 32 + hi * 8);

    f4t acc[4][2];
#pragma unroll
    for (int h = 0; h < 4; ++h) { acc[h][0] = 0.f; acc[h][1] = 0.f; }
    float ls[4] = {0.f, 0.f, 0.f, 0.f};

    const float* adjrow = adj + ((size_t)(b * C_) + qs) * C_;
    const unsigned short* Krow = Kb + ((size_t)(b * C_) + lo) * IND + hi * 8;
    const unsigned short* Vrow = Vt + ((size_t)(b * IND) + lo) * C_;

    const int NIT = KPW / 16;            // 16
    f4t adjv = *(const f4t*)(adjrow + k0base + hi * 4);

    for (int it = 0; it < NIT; ++it) {
        const int k0  = k0base + it * 16;
        const int itn = (it + 1 < NIT) ? it + 1 : it;
        const f4t adjn = *(const f4t*)(adjrow + k0base + itn * 16 + hi * 4);

        short8 kf[4];
        s4t vf[4][2];
#pragma unroll
        for (int h = 0; h < 4; ++h) {
            kf[h]    = *(const short8*)(Krow + (size_t)k0 * IND + h * 32);
            vf[h][0] = *(const s4t*)(Vrow + (size_t)(h * 32) * C_ + k0 + hi * 4);
            vf[h][1] = *(const s4t*)(Vrow + (size_t)(h * 32 + 16) * C_ + k0 + hi * 4);
        }

#pragma unroll
        for (int h = 0; h < 4; ++h) {
            // St[k][q]: lane owns q=lo, k = k0 + hi*4 + r  (C-layout)
            f4t st = __builtin_amdgcn_mfma_f32_16x16x32_bf16(
                kf[h], qf[h], (f4t)0.f, 0, 0, 0);
            float p[4];
#pragma unroll
            for (int r = 0; r < 4; ++r) {
                const float a = st[r] * adjv[r];         // adj gate (pre-leaky)
                const float m = fmaxf(a, 0.2f * a);      // LeakyReLU(0.2)
                p[r] = exp2f(m);                         // e^s (L2E pre-folded)
                ls[h] += p[r];
            }
            const s4t pp = pack4_bf16(p[0], p[1], p[2], p[3]);
            // PV: A=P (already in A-frag layout), B=V columns from Vt
            acc[h][0] = MFMA16(pp, vf[h][0], acc[h][0]);
            acc[h][1] = MFMA16(pp, vf[h][1], acc[h][1]);
        }
        adjv = adjn;
    }

    // reduce l over the 4 lane-groups (k quarters) within the wave
#pragma unroll
    for (int h = 0; h < 4; ++h) {
        ls[h] += __shfl_xor(ls[h], 16, 64);
        ls[h] += __shfl_xor(ls[h], 32, 64);
    }
    // lane keeps l for head=hi, q=qs
    const float lw = (hi == 0) ? ls[0] : (hi == 1) ? ls[1] : (hi == 2) ? ls[2] : ls[3];

    // cross-half reduction through LDS
    if (half == 1) {
#pragma unroll
        for (int h = 0; h < 4; ++h)
#pragma unroll
            for (int dh = 0; dh < 2; ++dh)
#pragma unroll
                for (int r = 0; r < 4; ++r)
                    redO[s][hi * 4 + r][h * 32 + dh * 16 + lo] = acc[h][dh][r];
        redL[s][hi * 16 + lo] = lw;
    }
    __syncthreads();
    if (half == 0) {
        float lsum = lw + redL[s][hi * 16 + lo];
#pragma unroll
        for (int h = 0; h < 4; ++h)
#pragma unroll
            for (int dh = 0; dh < 2; ++dh)
#pragma unroll
                for (int r = 0; r < 4; ++r)
                    acc[h][dh][r] += redO[s][hi * 4 + r][h * 32 + dh * 16 + lo];

        const size_t BHC   = (size_t)B_ * H_ * C_;
        const size_t obase = (size_t)kz * BHC;
        lpart[obase + (size_t)(b * H_ + hi) * C_ + qs] = lsum;

        // O: PV C-layout: lane owns q = q0+s*16+hi*4+reg, d = h*32+dh*16+lo
#pragma unroll
        for (int h = 0; h < 4; ++h) {
            const size_t rb = obase + (size_t)(b * H_ + h) * C_ + q0 + s * 16 + hi * 4;
#pragma unroll
            for (int dh = 0; dh < 2; ++dh)
#pragma unroll
                for (int r = 0; r < 4; ++r)
                    Opart[(rb + r) * D_ + dh * 16 + lo] = acc[h][dh][r];
        }
    }
}

// ---------------------------------------------------------------------------
// K3: combine split-K partials:  AO = (sum_kz O_kz) / (sum_kz l_kz)
// One thread per (row, float4-chunk): 2048 blocks for latency hiding.
__global__ __launch_bounds__(256) void combine_kernel(
    const float* __restrict__ Opart, const float* __restrict__ lpart,
    float* __restrict__ AO)
{
    const int cid = blockIdx.x * 256 + threadIdx.x;   // 0 .. 524287
    const int j   = cid & 7;                          // float4 chunk of D=32
    const int idx = cid >> 3;                         // (b*H+h)*C + q
    const int q  = idx & (C_ - 1);
    const int bh = idx >> 11;
    const int h  = bh & (H_ - 1);
    const int b  = bh >> 2;
    const size_t BHC = (size_t)B_ * H_ * C_;

    float4 acc = {0.f, 0.f, 0.f, 0.f};
    float lsum = 0.f;
#pragma unroll
    for (int kz = 0; kz < KSPLIT; ++kz) {
        const size_t base = (size_t)kz * BHC + idx;
        lsum += lpart[base];
        const float4 v = *(const float4*)(Opart + base * D_ + j * 4);
        acc.x += v.x; acc.y += v.y; acc.z += v.z; acc.w += v.w;
    }
    const float inv = 1.f / lsum;
    float4 o;
    o.x = acc.x * inv; o.y = acc.y * inv; o.z = acc.z * inv; o.w = acc.w * inv;
    *(float4*)(AO + ((size_t)(b * C_) + q) * IND + h * D_ + j * 4) = o;
}

// ---------------------------------------------------------------------------
// K4: output projection + bias (fp32).  out = AO @ Wo + bo
// 16 rows/block -> 1024 blocks; thread tile 2x4.
__global__ __launch_bounds__(256) void out_proj_kernel(
    const float* __restrict__ AO, const float* __restrict__ Wo,
    const float* __restrict__ bo, float* __restrict__ out)
{
    __shared__ float xs[16][IND];
    const int t = threadIdx.x;
    const size_t row0 = (size_t)blockIdx.x * 16;

    const float4* xsrc = (const float4*)(AO + row0 * IND);
    float4* xd = (float4*)&xs[0][0];
#pragma unroll
    for (int i = 0; i < 2; ++i) xd[t + i * 256] = xsrc[t + i * 256];
    __syncthreads();

    const int rg = t >> 5, cg = t & 31;
    const int r0 = rg * 2, c0 = cg * 4;

    float acc[2][4] = {};
#pragma unroll 4
    for (int k = 0; k < IND; ++k) {
        const float4 wv = *(const float4*)(Wo + k * IND + c0);
#pragma unroll
        for (int i = 0; i < 2; ++i) {
            const float xr = xs[r0 + i][k];
            acc[i][0] += xr * wv.x;
            acc[i][1] += xr * wv.y;
            acc[i][2] += xr * wv.z;
            acc[i][3] += xr * wv.w;
        }
    }
    const float4 bv = *(const float4*)(bo + c0);
    float* O = out + row0 * IND;
#pragma unroll
    for (int i = 0; i < 2; ++i) {
        float4 o;
        o.x = acc[i][0] + bv.x; o.y = acc[i][1] + bv.y;
        o.z = acc[i][2] + bv.z; o.w = acc[i][3] + bv.w;
        *(float4*)(O + (size_t)(r0 + i) * IND + c0) = o;
    }
}

// ---------------------------------------------------------------------------
extern "C" void kernel_launch(void* const* d_in, const int* in_sizes, int n_in,
                              void* d_out, int out_size, void* d_ws, size_t ws_size,
                              hipStream_t stream) {
    const float* x   = (const float*)d_in[0];
    const float* adj = (const float*)d_in[1];
    const float* Wq  = (const float*)d_in[2];
    const float* Wk  = (const float*)d_in[3];
    const float* Wv  = (const float*)d_in[4];
    const float* Wo  = (const float*)d_in[5];
    const float* bo  = (const float*)d_in[6];
    float* out = (float*)d_out;

    // workspace: Qb,Kb,Vt bf16 (4.2MB each); AO fp32 8.4MB;
    // Opart fp32 33.6MB (KSPLIT=4); lpart 1MB  -> 55.6 MB total (fits;
    // 90 MB @ KSPLIT=8 overflowed ws and corrupted neighboring buffers)
    unsigned short* Qb = (unsigned short*)d_ws;
    unsigned short* Kb = Qb + (size_t)M_ * IND;
    unsigned short* Vt = Kb + (size_t)M_ * IND;
    float* AO    = (float*)(Vt + (size_t)M_ * IND);
    float* Opart = AO + (size_t)M_ * IND;
    float* lpart = Opart + (size_t)KSPLIT * B_ * H_ * C_ * D_;

    hipLaunchKernelGGL(qkv_proj_kernel, dim3(M_ / 16), dim3(256), 0, stream,
                       x, Wq, Wk, Wv, Qb, Kb, Vt);
    hipLaunchKernelGGL(attn_kernel, dim3(C_ / 32, B_, KSPLIT), dim3(256), 0, stream,
                       Qb, Kb, Vt, adj, Opart, lpart);
    hipLaunchKernelGGL(combine_kernel, dim3(B_ * H_ * C_ * 8 / 256), dim3(256), 0, stream,
                       Opart, lpart, AO);
    hipLaunchKernelGGL(out_proj_kernel, dim3(M_ / 16), dim3(256), 0, stream,
                       AO, Wo, bo, out);
}

// Round 6
// 455.559 us; speedup vs baseline: 1.3287x; 1.3287x over previous
//
#include <hip/hip_runtime.h>
#include <hip/hip_bf16.h>

// Problem constants (GATLayer): B=8, C=2048, IN=OUT=128, H=4, D=32
constexpr int B_  = 8;
constexpr int C_  = 2048;
constexpr int IND = 128;
constexpr int H_  = 4;
constexpr int D_  = 32;
constexpr int M_  = B_ * C_;          // 16384 tokens
constexpr float QSCALE = 0.17677669529663687f;   // 1/sqrt(32)
constexpr float L2E    = 1.4426950408889634f;
constexpr float QL2    = QSCALE * L2E;           // folded: exp2 needs no mul

constexpr int KSPLIT = 4;             // global split (Opart = 33.6 MB, ws fits)
constexpr int KPG = C_ / KSPLIT;      // 512 keys per (block, kz)

typedef __attribute__((ext_vector_type(8))) short short8;
typedef __attribute__((ext_vector_type(4))) short s4t;
typedef __attribute__((ext_vector_type(4))) float f4t;
typedef __attribute__((ext_vector_type(4))) unsigned short us4;
typedef __attribute__((ext_vector_type(2))) unsigned short us2;

// Device pass has this builtin; host pass doesn't advertise it via
// __has_builtin, so give the host a dummy (never executed).
#if __has_builtin(__builtin_amdgcn_mfma_f32_16x16x16bf16_1k)
#define MFMA16(a, b, c) __builtin_amdgcn_mfma_f32_16x16x16bf16_1k(a, b, c, 0, 0, 0)
#else
#define MFMA16(a, b, c) (c)   // host-pass placeholder
#endif

__device__ __forceinline__ unsigned short f2bf(float f) {
    union { float f; unsigned u; } v; v.f = f;
    unsigned u = v.u + 0x7fffu + ((v.u >> 16) & 1u);   // RNE
    return (unsigned short)(u >> 16);
}

// Pack 4 floats -> 4 bf16 (RNE). v_cvt_pk_bf16_f32 on device pass.
__device__ __forceinline__ s4t pack4_bf16(float p0, float p1, float p2, float p3) {
#if __has_builtin(__builtin_amdgcn_cvt_pk_bf16_f32)
    auto a = __builtin_amdgcn_cvt_pk_bf16_f32(p0, p1);
    auto b = __builtin_amdgcn_cvt_pk_bf16_f32(p2, p3);
    unsigned u[2];
    __builtin_memcpy(&u[0], &a, 4);
    __builtin_memcpy(&u[1], &b, 4);
    s4t pp;
    __builtin_memcpy(&pp, u, 8);
    return pp;
#else
    s4t pp;
    pp[0] = (short)f2bf(p0); pp[1] = (short)f2bf(p1);
    pp[2] = (short)f2bf(p2); pp[3] = (short)f2bf(p3);
    return pp;
#endif
}

// ---------------------------------------------------------------------------
// K1: fused QKV projection (fp32 compute, bf16 outputs).
// 16 rows/block -> 1024 blocks; thread tile 2x4.
// Qb scaled by (1/sqrt(D))*log2(e).  Vt is V transposed: Vt[b][d(128)][c].
__global__ __launch_bounds__(256) void qkv_proj_kernel(
    const float* __restrict__ x,
    const float* __restrict__ Wq, const float* __restrict__ Wk,
    const float* __restrict__ Wv,
    unsigned short* __restrict__ Qb, unsigned short* __restrict__ Kb,
    unsigned short* __restrict__ Vt)
{
    __shared__ float xs[16][IND];   // 8 KB
    const int t = threadIdx.x;
    const size_t row0 = (size_t)blockIdx.x * 16;

    const float4* xsrc = (const float4*)(x + row0 * IND);
    float4* xd = (float4*)&xs[0][0];
#pragma unroll
    for (int i = 0; i < 2; ++i) xd[t + i * 256] = xsrc[t + i * 256];
    __syncthreads();

    const int rg = t >> 5, cg = t & 31;
    const int r0 = rg * 2, c0 = cg * 4;
    const int b  = (int)(row0 >> 11);
    const int cb = (int)(row0 & 2047);

#pragma unroll
    for (int w = 0; w < 3; ++w) {
        const float* __restrict__ W = (w == 0) ? Wq : (w == 1) ? Wk : Wv;
        float acc[2][4] = {};
#pragma unroll 4
        for (int k = 0; k < IND; ++k) {
            const float4 wv = *(const float4*)(W + k * IND + c0);
#pragma unroll
            for (int i = 0; i < 2; ++i) {
                const float xr = xs[r0 + i][k];
                acc[i][0] += xr * wv.x;
                acc[i][1] += xr * wv.y;
                acc[i][2] += xr * wv.z;
                acc[i][3] += xr * wv.w;
            }
        }
        if (w == 2) {
            // transposed store: Vt[(b*128 + d)*C + c], 2 consecutive tokens
#pragma unroll
            for (int jj = 0; jj < 4; ++jj) {
                us2 v;
                v[0] = f2bf(acc[0][jj]);
                v[1] = f2bf(acc[1][jj]);
                *(us2*)(Vt + ((size_t)(b * IND + c0 + jj)) * C_ + cb + r0) = v;
            }
        } else {
            const float sc = (w == 0) ? QL2 : 1.0f;
            unsigned short* O = (w == 0) ? Qb : Kb;
#pragma unroll
            for (int i = 0; i < 2; ++i) {
                us4 v;
#pragma unroll
                for (int j = 0; j < 4; ++j) v[j] = f2bf(acc[i][j] * sc);
                *(us4*)(O + (row0 + r0 + i) * IND + c0) = v;
            }
        }
    }
}

// ---------------------------------------------------------------------------
// K2: MFMA flash attention. Scores computed TRANSPOSED so the probability
// tile lands directly in the 16x16x16 PV A-fragment layout. No LDS.
// Wave = 2 heads x 16 q-rows x 512 keys (heads split across waves instead of
// K: disjoint outputs -> no reduction, no barrier, low VGPR pressure).
// Block = 256 = 4 waves = 2 q-subtiles x 2 head-halves.
// Grid = 64 x 8 x 4 = 2048 blocks = 8192 waves = 8 waves/SIMD.
__global__ __launch_bounds__(256) void attn_kernel(
    const unsigned short* __restrict__ Qb, const unsigned short* __restrict__ Kb,
    const unsigned short* __restrict__ Vt, const float* __restrict__ adj,
    float* __restrict__ Opart, float* __restrict__ lpart)
{
    const int t  = threadIdx.x;
    const int w  = t >> 6;
    const int s  = w & 1;                // q-subtile (0/1)
    const int hh = w >> 1;               // head-half: heads {2hh, 2hh+1}
    const int l  = t & 63;
    const int lo = l & 15, hi = l >> 4;
    const int b  = blockIdx.y;
    const int kz = blockIdx.z;
    const int q0 = blockIdx.x * 32;
    const int qs = q0 + s * 16 + lo;     // this lane's q row (0..2047)
    const int k0base = kz * KPG;

    // Q fragments (B-operand of St MFMA): lane holds Q[qs][(2hh+h)*32 + hi*8..]
    short8 qf[2];
#pragma unroll
    for (int h = 0; h < 2; ++h)
        qf[h] = *(const short8*)(Qb + ((size_t)(b * C_) + qs) * IND +
                                 (hh * 2 + h) * 32 + hi * 8);

    f4t acc[2][2];
    acc[0][0] = 0.f; acc[0][1] = 0.f; acc[1][0] = 0.f; acc[1][1] = 0.f;
    float ls[2] = {0.f, 0.f};

    const float* adjrow = adj + ((size_t)(b * C_) + qs) * C_;
    const unsigned short* Krow = Kb + ((size_t)(b * C_) + lo) * IND + hh * 64 + hi * 8;
    const unsigned short* Vrow = Vt + ((size_t)(b * IND) + hh * 64 + lo) * C_;

    const int NIT = KPG / 16;            // 32
    f4t adjv = *(const f4t*)(adjrow + k0base + hi * 4);

    for (int it = 0; it < NIT; ++it) {
        const int k0  = k0base + it * 16;
        const int itn = (it + 1 < NIT) ? it + 1 : it;
        const f4t adjn = *(const f4t*)(adjrow + k0base + itn * 16 + hi * 4);

        short8 kf[2];
        s4t vf[2][2];
#pragma unroll
        for (int h = 0; h < 2; ++h) {
            kf[h]    = *(const short8*)(Krow + (size_t)k0 * IND + h * 32);
            vf[h][0] = *(const s4t*)(Vrow + (size_t)(h * 32) * C_ + k0 + hi * 4);
            vf[h][1] = *(const s4t*)(Vrow + (size_t)(h * 32 + 16) * C_ + k0 + hi * 4);
        }

#pragma unroll
        for (int h = 0; h < 2; ++h) {
            // St[k][q]: lane owns q=lo, k = k0 + hi*4 + r  (C-layout)
            f4t st = __builtin_amdgcn_mfma_f32_16x16x32_bf16(
                kf[h], qf[h], (f4t)0.f, 0, 0, 0);
            float p[4];
#pragma unroll
            for (int r = 0; r < 4; ++r) {
                const float a = st[r] * adjv[r];         // adj gate (pre-leaky)
                const float m = fmaxf(a, 0.2f * a);      // LeakyReLU(0.2)
                p[r] = exp2f(m);                         // e^s (L2E pre-folded)
                ls[h] += p[r];
            }
            const s4t pp = pack4_bf16(p[0], p[1], p[2], p[3]);
            // PV: A=P (already in A-frag layout), B=V columns from Vt
            acc[h][0] = MFMA16(pp, vf[h][0], acc[h][0]);
            acc[h][1] = MFMA16(pp, vf[h][1], acc[h][1]);
        }
        adjv = adjn;
    }

    // reduce l over the 4 lane-groups (k quarters) within the wave
#pragma unroll
    for (int h = 0; h < 2; ++h) {
        ls[h] += __shfl_xor(ls[h], 16, 64);
        ls[h] += __shfl_xor(ls[h], 32, 64);
    }

    const size_t BHC   = (size_t)B_ * H_ * C_;
    const size_t obase = (size_t)kz * BHC;

    // lanes hi=0/1 write l for heads 2hh / 2hh+1
    if (hi < 2) {
        const float lw = (hi == 0) ? ls[0] : ls[1];
        lpart[obase + (size_t)(b * H_ + hh * 2 + hi) * C_ + qs] = lw;
    }

    // O: PV C-layout: lane owns q = q0+s*16+hi*4+r, d = (2hh+h)*32+dh*16+lo
#pragma unroll
    for (int h = 0; h < 2; ++h) {
        const size_t rb = obase + (size_t)(b * H_ + hh * 2 + h) * C_ +
                          q0 + s * 16 + hi * 4;
#pragma unroll
        for (int dh = 0; dh < 2; ++dh)
#pragma unroll
            for (int r = 0; r < 4; ++r)
                Opart[(rb + r) * D_ + dh * 16 + lo] = acc[h][dh][r];
    }
}

// ---------------------------------------------------------------------------
// K3: combine split-K partials:  AO = (sum_kz O_kz) / (sum_kz l_kz)
// One thread per (row, float4-chunk): 2048 blocks for latency hiding.
__global__ __launch_bounds__(256) void combine_kernel(
    const float* __restrict__ Opart, const float* __restrict__ lpart,
    float* __restrict__ AO)
{
    const int cid = blockIdx.x * 256 + threadIdx.x;   // 0 .. 524287
    const int j   = cid & 7;                          // float4 chunk of D=32
    const int idx = cid >> 3;                         // (b*H+h)*C + q
    const int q  = idx & (C_ - 1);
    const int bh = idx >> 11;
    const int h  = bh & (H_ - 1);
    const int b  = bh >> 2;
    const size_t BHC = (size_t)B_ * H_ * C_;

    float4 acc = {0.f, 0.f, 0.f, 0.f};
    float lsum = 0.f;
#pragma unroll
    for (int kz = 0; kz < KSPLIT; ++kz) {
        const size_t base = (size_t)kz * BHC + idx;
        lsum += lpart[base];
        const float4 v = *(const float4*)(Opart + base * D_ + j * 4);
        acc.x += v.x; acc.y += v.y; acc.z += v.z; acc.w += v.w;
    }
    const float inv = 1.f / lsum;
    float4 o;
    o.x = acc.x * inv; o.y = acc.y * inv; o.z = acc.z * inv; o.w = acc.w * inv;
    *(float4*)(AO + ((size_t)(b * C_) + q) * IND + h * D_ + j * 4) = o;
}

// ---------------------------------------------------------------------------
// K4: output projection + bias (fp32).  out = AO @ Wo + bo
// 16 rows/block -> 1024 blocks; thread tile 2x4.
__global__ __launch_bounds__(256) void out_proj_kernel(
    const float* __restrict__ AO, const float* __restrict__ Wo,
    const float* __restrict__ bo, float* __restrict__ out)
{
    __shared__ float xs[16][IND];
    const int t = threadIdx.x;
    const size_t row0 = (size_t)blockIdx.x * 16;

    const float4* xsrc = (const float4*)(AO + row0 * IND);
    float4* xd = (float4*)&xs[0][0];
#pragma unroll
    for (int i = 0; i < 2; ++i) xd[t + i * 256] = xsrc[t + i * 256];
    __syncthreads();

    const int rg = t >> 5, cg = t & 31;
    const int r0 = rg * 2, c0 = cg * 4;

    float acc[2][4] = {};
#pragma unroll 4
    for (int k = 0; k < IND; ++k) {
        const float4 wv = *(const float4*)(Wo + k * IND + c0);
#pragma unroll
        for (int i = 0; i < 2; ++i) {
            const float xr = xs[r0 + i][k];
            acc[i][0] += xr * wv.x;
            acc[i][1] += xr * wv.y;
            acc[i][2] += xr * wv.z;
            acc[i][3] += xr * wv.w;
        }
    }
    const float4 bv = *(const float4*)(bo + c0);
    float* O = out + row0 * IND;
#pragma unroll
    for (int i = 0; i < 2; ++i) {
        float4 o;
        o.x = acc[i][0] + bv.x; o.y = acc[i][1] + bv.y;
        o.z = acc[i][2] + bv.z; o.w = acc[i][3] + bv.w;
        *(float4*)(O + (size_t)(r0 + i) * IND + c0) = o;
    }
}

// ---------------------------------------------------------------------------
extern "C" void kernel_launch(void* const* d_in, const int* in_sizes, int n_in,
                              void* d_out, int out_size, void* d_ws, size_t ws_size,
                              hipStream_t stream) {
    const float* x   = (const float*)d_in[0];
    const float* adj = (const float*)d_in[1];
    const float* Wq  = (const float*)d_in[2];
    const float* Wk  = (const float*)d_in[3];
    const float* Wv  = (const float*)d_in[4];
    const float* Wo  = (const float*)d_in[5];
    const float* bo  = (const float*)d_in[6];
    float* out = (float*)d_out;

    // workspace: Qb,Kb,Vt bf16 (4.2MB each); AO fp32 8.4MB;
    // Opart fp32 33.6MB (KSPLIT=4); lpart 1MB  -> 55.6 MB total
    unsigned short* Qb = (unsigned short*)d_ws;
    unsigned short* Kb = Qb + (size_t)M_ * IND;
    unsigned short* Vt = Kb + (size_t)M_ * IND;
    float* AO    = (float*)(Vt + (size_t)M_ * IND);
    float* Opart = AO + (size_t)M_ * IND;
    float* lpart = Opart + (size_t)KSPLIT * B_ * H_ * C_ * D_;

    hipLaunchKernelGGL(qkv_proj_kernel, dim3(M_ / 16), dim3(256), 0, stream,
                       x, Wq, Wk, Wv, Qb, Kb, Vt);
    hipLaunchKernelGGL(attn_kernel, dim3(C_ / 32, B_, KSPLIT), dim3(256), 0, stream,
                       Qb, Kb, Vt, adj, Opart, lpart);
    hipLaunchKernelGGL(combine_kernel, dim3(B_ * H_ * C_ * 8 / 256), dim3(256), 0, stream,
                       Opart, lpart, AO);
    hipLaunchKernelGGL(out_proj_kernel, dim3(M_ / 16), dim3(256), 0, stream,
                       AO, Wo, bo, out);
}

// Round 7
// 408.763 us; speedup vs baseline: 1.4808x; 1.1145x over previous
//
#include <hip/hip_runtime.h>
#include <hip/hip_bf16.h>

// Problem constants (GATLayer): B=8, C=2048, IN=OUT=128, H=4, D=32
constexpr int B_  = 8;
constexpr int C_  = 2048;
constexpr int IND = 128;
constexpr int H_  = 4;
constexpr int D_  = 32;
constexpr int M_  = B_ * C_;          // 16384 tokens
constexpr float QSCALE = 0.17677669529663687f;   // 1/sqrt(32)
constexpr float L2E    = 1.4426950408889634f;
constexpr float QL2    = QSCALE * L2E;           // folded into Wt Q-rows

constexpr int KSPLIT = 4;             // global split (Opart = 33.6 MB, ws fits)
constexpr int KPG = C_ / KSPLIT;      // 512 keys per (block, kz)

typedef __attribute__((ext_vector_type(8))) short short8;
typedef __attribute__((ext_vector_type(4))) short s4t;
typedef __attribute__((ext_vector_type(4))) float f4t;
typedef __attribute__((ext_vector_type(4))) unsigned short us4;

// Device pass has these; host pass doesn't advertise via __has_builtin.
#if __has_builtin(__builtin_amdgcn_mfma_f32_16x16x16bf16_1k)
#define MFMA16(a, b, c) __builtin_amdgcn_mfma_f32_16x16x16bf16_1k(a, b, c, 0, 0, 0)
#else
#define MFMA16(a, b, c) (c)   // host-pass placeholder
#endif
#define MFMA32(a, b, c) __builtin_amdgcn_mfma_f32_16x16x32_bf16(a, b, c, 0, 0, 0)

__device__ __forceinline__ unsigned short f2bf(float f) {
    union { float f; unsigned u; } v; v.f = f;
    unsigned u = v.u + 0x7fffu + ((v.u >> 16) & 1u);   // RNE
    return (unsigned short)(u >> 16);
}

__device__ __forceinline__ s4t pack4_bf16(float p0, float p1, float p2, float p3) {
#if __has_builtin(__builtin_amdgcn_cvt_pk_bf16_f32)
    auto a = __builtin_amdgcn_cvt_pk_bf16_f32(p0, p1);
    auto b = __builtin_amdgcn_cvt_pk_bf16_f32(p2, p3);
    unsigned u[2];
    __builtin_memcpy(&u[0], &a, 4);
    __builtin_memcpy(&u[1], &b, 4);
    s4t pp;
    __builtin_memcpy(&pp, u, 8);
    return pp;
#else
    s4t pp;
    pp[0] = (short)f2bf(p0); pp[1] = (short)f2bf(p1);
    pp[2] = (short)f2bf(p2); pp[3] = (short)f2bf(p3);
    return pp;
#endif
}

__device__ __forceinline__ short8 cvt8(float4 a, float4 b) {
    s4t x = pack4_bf16(a.x, a.y, a.z, a.w);
    s4t y = pack4_bf16(b.x, b.y, b.z, b.w);
    short8 r;
    r[0] = x[0]; r[1] = x[1]; r[2] = x[2]; r[3] = x[3];
    r[4] = y[0]; r[5] = y[1]; r[6] = y[2]; r[7] = y[3];
    return r;
}

// ---------------------------------------------------------------------------
// K0: weight prep. Wtb[512][128] bf16: row n = column n of the fused weight
// [Wq*QL2 | Wk | Wv | Wo].  LDS tile transpose, padded stride (130) to dodge
// bank conflicts. Grid 32 blocks x 256 threads; block handles 16 Wtb rows.
__global__ __launch_bounds__(256) void prep_w_kernel(
    const float* __restrict__ Wq, const float* __restrict__ Wk,
    const float* __restrict__ Wv, const float* __restrict__ Wo,
    unsigned short* __restrict__ Wtb)
{
    __shared__ unsigned short lds[16][130];
    const int t  = threadIdx.x;
    const int n0 = blockIdx.x * 16;          // 0..511 in steps of 16

    // source selection is block-uniform (sections are multiples of 128)
    const float* src; int nb; float sc = 1.0f;
    if      (n0 < 128) { src = Wq; nb = n0;       sc = QL2; }
    else if (n0 < 256) { src = Wk; nb = n0 - 128; }
    else if (n0 < 384) { src = Wv; nb = n0 - 256; }
    else               { src = Wo; nb = n0 - 384; }

    const int nn = t & 15, kk = t >> 4;      // kk: 0..15
#pragma unroll
    for (int kb = 0; kb < 8; ++kb) {
        const int k = kb * 16 + kk;
        lds[nn][k] = f2bf(src[k * IND + nb + nn] * sc);
    }
    __syncthreads();
    const int k = t & 127, rr = t >> 7;      // rr: 0..1
#pragma unroll
    for (int it = 0; it < 8; ++it) {
        const int r = it * 2 + rr;
        Wtb[(size_t)(n0 + r) * IND + k] = lds[r][k];
    }
}

// ---------------------------------------------------------------------------
// K1: QKV projection via MFMA. Block = 192 threads = 3 waves (one per matrix),
// 16 tokens per block, grid 1024.  Q/K computed TRANSPOSED (coalesced 8B row
// stores); V computed normal -> lands directly in Vt[b][d][c] layout.
__global__ __launch_bounds__(192) void qkv_proj_kernel(
    const float* __restrict__ x, const unsigned short* __restrict__ Wtb,
    unsigned short* __restrict__ Qb, unsigned short* __restrict__ Kb,
    unsigned short* __restrict__ Vt)
{
    const int t = threadIdx.x;
    const int w = t >> 6;                // 0:Q 1:K 2:V
    const int l = t & 63;
    const int lo = l & 15, hi = l >> 4;
    const int tok0 = blockIdx.x * 16;
    const int b  = tok0 >> 11;
    const int cb = tok0 & 2047;

    // x fragments: lane holds x[tok0+lo][kc*32 + hi*8 .. +8] as bf16
    short8 xb[4];
    const float* xrow = x + (size_t)(tok0 + lo) * IND;
#pragma unroll
    for (int kc = 0; kc < 4; ++kc) {
        const float4 a = *(const float4*)(xrow + kc * 32 + hi * 8);
        const float4 c = *(const float4*)(xrow + kc * 32 + hi * 8 + 4);
        xb[kc] = cvt8(a, c);
    }

    const unsigned short* wbase = Wtb + (size_t)(w * 128) * IND;
#pragma unroll
    for (int tile = 0; tile < 8; ++tile) {
        const int n0 = tile * 16;
        short8 wf[4];
#pragma unroll
        for (int kc = 0; kc < 4; ++kc)
            wf[kc] = *(const short8*)(wbase + (size_t)(n0 + lo) * IND +
                                      kc * 32 + hi * 8);
        f4t acc = 0.f;
        if (w < 2) {
            // Yt = Wt-rows x x-rows: lane owns token=lo, cols n0+hi*4+r
#pragma unroll
            for (int kc = 0; kc < 4; ++kc) acc = MFMA32(wf[kc], xb[kc], acc);
            us4 v;
#pragma unroll
            for (int r = 0; r < 4; ++r) v[r] = f2bf(acc[r]);
            unsigned short* O = (w == 0) ? Qb : Kb;
            *(us4*)(O + (size_t)(tok0 + lo) * IND + n0 + hi * 4) = v;
        } else {
            // Y = x-rows x W-cols: lane owns d=n0+lo, tokens cb+hi*4+r
#pragma unroll
            for (int kc = 0; kc < 4; ++kc) acc = MFMA32(xb[kc], wf[kc], acc);
            us4 v;
#pragma unroll
            for (int r = 0; r < 4; ++r) v[r] = f2bf(acc[r]);
            *(us4*)(Vt + ((size_t)(b * IND) + n0 + lo) * C_ + cb + hi * 4) = v;
        }
    }
}

// ---------------------------------------------------------------------------
// K2: MFMA flash attention, software-pipelined: kf/vf prefetched 1 iteration
// ahead, adj (HBM-latency) 2 ahead. Wave = 2 heads x 16 q x 512 keys; no LDS,
// disjoint outputs. Grid 64 x 8 x 4 = 8192 waves.
__global__ __launch_bounds__(256) void attn_kernel(
    const unsigned short* __restrict__ Qb, const unsigned short* __restrict__ Kb,
    const unsigned short* __restrict__ Vt, const float* __restrict__ adj,
    float* __restrict__ Opart, float* __restrict__ lpart)
{
    const int t  = threadIdx.x;
    const int w  = t >> 6;
    const int s  = w & 1;                // q-subtile (0/1)
    const int hh = w >> 1;               // head-half: heads {2hh, 2hh+1}
    const int l  = t & 63;
    const int lo = l & 15, hi = l >> 4;
    const int b  = blockIdx.y;
    const int kz = blockIdx.z;
    const int q0 = blockIdx.x * 32;
    const int qs = q0 + s * 16 + lo;
    const int k0base = kz * KPG;

    short8 qf[2];
#pragma unroll
    for (int h = 0; h < 2; ++h)
        qf[h] = *(const short8*)(Qb + ((size_t)(b * C_) + qs) * IND +
                                 (hh * 2 + h) * 32 + hi * 8);

    f4t acc[2][2];
    acc[0][0] = 0.f; acc[0][1] = 0.f; acc[1][0] = 0.f; acc[1][1] = 0.f;
    float ls[2] = {0.f, 0.f};

    const float* adjrow = adj + ((size_t)(b * C_) + qs) * C_;
    const unsigned short* Krow = Kb + ((size_t)(b * C_) + lo) * IND + hh * 64 + hi * 8;
    const unsigned short* Vrow = Vt + ((size_t)(b * IND) + hh * 64 + lo) * C_;

    const int NIT = KPG / 16;            // 32

    // pipeline priming: adj 2 stages, kf/vf 1 stage
    f4t adj0 = *(const f4t*)(adjrow + k0base + hi * 4);
    f4t adj1 = *(const f4t*)(adjrow + k0base + 16 + hi * 4);
    short8 kf0[2];
    s4t vf0[2][2];
#pragma unroll
    for (int h = 0; h < 2; ++h) {
        kf0[h]    = *(const short8*)(Krow + (size_t)k0base * IND + h * 32);
        vf0[h][0] = *(const s4t*)(Vrow + (size_t)(h * 32) * C_ + k0base + hi * 4);
        vf0[h][1] = *(const s4t*)(Vrow + (size_t)(h * 32 + 16) * C_ + k0base + hi * 4);
    }

    for (int it = 0; it < NIT; ++it) {
        const int itk = (it + 1 < NIT) ? it + 1 : it;
        const int ita = (it + 2 < NIT) ? it + 2 : NIT - 1;
        const int kk1 = k0base + itk * 16;

        // issue next-stage loads first (use-distance = one full iteration)
        short8 kf1[2];
        s4t vf1[2][2];
#pragma unroll
        for (int h = 0; h < 2; ++h) {
            kf1[h]    = *(const short8*)(Krow + (size_t)kk1 * IND + h * 32);
            vf1[h][0] = *(const s4t*)(Vrow + (size_t)(h * 32) * C_ + kk1 + hi * 4);
            vf1[h][1] = *(const s4t*)(Vrow + (size_t)(h * 32 + 16) * C_ + kk1 + hi * 4);
        }
        const f4t adj2 = *(const f4t*)(adjrow + k0base + ita * 16 + hi * 4);

        // compute on stage-0 registers
#pragma unroll
        for (int h = 0; h < 2; ++h) {
            f4t st = MFMA32(kf0[h], qf[h], (f4t)0.f);
            float p[4];
#pragma unroll
            for (int r = 0; r < 4; ++r) {
                const float a = st[r] * adj0[r];
                const float m = fmaxf(a, 0.2f * a);      // LeakyReLU(0.2)
                p[r] = exp2f(m);                         // e^s (L2E pre-folded)
                ls[h] += p[r];
            }
            const s4t pp = pack4_bf16(p[0], p[1], p[2], p[3]);
            acc[h][0] = MFMA16(pp, vf0[h][0], acc[h][0]);
            acc[h][1] = MFMA16(pp, vf0[h][1], acc[h][1]);
        }
        // rotate pipeline
        adj0 = adj1; adj1 = adj2;
#pragma unroll
        for (int h = 0; h < 2; ++h) {
            kf0[h] = kf1[h]; vf0[h][0] = vf1[h][0]; vf0[h][1] = vf1[h][1];
        }
    }

#pragma unroll
    for (int h = 0; h < 2; ++h) {
        ls[h] += __shfl_xor(ls[h], 16, 64);
        ls[h] += __shfl_xor(ls[h], 32, 64);
    }

    const size_t BHC   = (size_t)B_ * H_ * C_;
    const size_t obase = (size_t)kz * BHC;

    if (hi < 2) {
        const float lw = (hi == 0) ? ls[0] : ls[1];
        lpart[obase + (size_t)(b * H_ + hh * 2 + hi) * C_ + qs] = lw;
    }

#pragma unroll
    for (int h = 0; h < 2; ++h) {
        const size_t rb = obase + (size_t)(b * H_ + hh * 2 + h) * C_ +
                          q0 + s * 16 + hi * 4;
#pragma unroll
        for (int dh = 0; dh < 2; ++dh)
#pragma unroll
            for (int r = 0; r < 4; ++r)
                Opart[(rb + r) * D_ + dh * 16 + lo] = acc[h][dh][r];
    }
}

// ---------------------------------------------------------------------------
// K3: combine split-K partials -> AOb (bf16):  AOb = (sum O_kz)/(sum l_kz)
__global__ __launch_bounds__(256) void combine_kernel(
    const float* __restrict__ Opart, const float* __restrict__ lpart,
    unsigned short* __restrict__ AOb)
{
    const int cid = blockIdx.x * 256 + threadIdx.x;   // 0 .. 524287
    const int j   = cid & 7;                          // float4 chunk of D=32
    const int idx = cid >> 3;                         // (b*H+h)*C + q
    const int q  = idx & (C_ - 1);
    const int bh = idx >> 11;
    const int h  = bh & (H_ - 1);
    const int b  = bh >> 2;
    const size_t BHC = (size_t)B_ * H_ * C_;

    float4 acc = {0.f, 0.f, 0.f, 0.f};
    float lsum = 0.f;
#pragma unroll
    for (int kz = 0; kz < KSPLIT; ++kz) {
        const size_t base = (size_t)kz * BHC + idx;
        lsum += lpart[base];
        const float4 v = *(const float4*)(Opart + base * D_ + j * 4);
        acc.x += v.x; acc.y += v.y; acc.z += v.z; acc.w += v.w;
    }
    const float inv = 1.f / lsum;
    us4 o;
    o[0] = f2bf(acc.x * inv); o[1] = f2bf(acc.y * inv);
    o[2] = f2bf(acc.z * inv); o[3] = f2bf(acc.w * inv);
    *(us4*)(AOb + ((size_t)(b * C_) + q) * IND + h * D_ + j * 4) = o;
}

// ---------------------------------------------------------------------------
// K4: output projection via MFMA (transposed-compute -> coalesced float4
// stores with fused bias). Block = 256 = 2 token-groups x 2 N-halves;
// 32 tokens/block, grid 512.
__global__ __launch_bounds__(256) void out_proj_kernel(
    const unsigned short* __restrict__ AOb, const unsigned short* __restrict__ Wtb,
    const float* __restrict__ bo, float* __restrict__ out)
{
    const int t  = threadIdx.x;
    const int w  = t >> 6;
    const int tg = w & 1, nh = w >> 1;
    const int l  = t & 63;
    const int lo = l & 15, hi = l >> 4;
    const int tok0 = blockIdx.x * 32 + tg * 16;

    short8 af[4];
    const unsigned short* arow = AOb + (size_t)(tok0 + lo) * IND;
#pragma unroll
    for (int kc = 0; kc < 4; ++kc)
        af[kc] = *(const short8*)(arow + kc * 32 + hi * 8);

    const unsigned short* wbase = Wtb + (size_t)384 * IND;
#pragma unroll
    for (int tile = 0; tile < 4; ++tile) {
        const int n0 = nh * 64 + tile * 16;
        short8 wf[4];
#pragma unroll
        for (int kc = 0; kc < 4; ++kc)
            wf[kc] = *(const short8*)(wbase + (size_t)(n0 + lo) * IND +
                                      kc * 32 + hi * 8);
        f4t acc = 0.f;
#pragma unroll
        for (int kc = 0; kc < 4; ++kc) acc = MFMA32(wf[kc], af[kc], acc);
        const f4t bv = *(const f4t*)(bo + n0 + hi * 4);
        float4 o;
        o.x = acc[0] + bv[0]; o.y = acc[1] + bv[1];
        o.z = acc[2] + bv[2]; o.w = acc[3] + bv[3];
        *(float4*)(out + (size_t)(tok0 + lo) * IND + n0 + hi * 4) = o;
    }
}

// ---------------------------------------------------------------------------
extern "C" void kernel_launch(void* const* d_in, const int* in_sizes, int n_in,
                              void* d_out, int out_size, void* d_ws, size_t ws_size,
                              hipStream_t stream) {
    const float* x   = (const float*)d_in[0];
    const float* adj = (const float*)d_in[1];
    const float* Wq  = (const float*)d_in[2];
    const float* Wk  = (const float*)d_in[3];
    const float* Wv  = (const float*)d_in[4];
    const float* Wo  = (const float*)d_in[5];
    const float* bo  = (const float*)d_in[6];
    float* out = (float*)d_out;

    // workspace (bf16 elems unless noted): Wtb 128KB; Qb/Kb/Vt 4.2MB each;
    // AOb 4.2MB; Opart fp32 33.6MB; lpart fp32 1MB  -> ~47.5 MB total
    unsigned short* Wtb = (unsigned short*)d_ws;
    unsigned short* Qb  = Wtb + (size_t)512 * IND;
    unsigned short* Kb  = Qb + (size_t)M_ * IND;
    unsigned short* Vt  = Kb + (size_t)M_ * IND;
    unsigned short* AOb = Vt + (size_t)M_ * IND;
    float* Opart = (float*)(AOb + (size_t)M_ * IND);
    float* lpart = Opart + (size_t)KSPLIT * B_ * H_ * C_ * D_;

    hipLaunchKernelGGL(prep_w_kernel, dim3(32), dim3(256), 0, stream,
                       Wq, Wk, Wv, Wo, Wtb);
    hipLaunchKernelGGL(qkv_proj_kernel, dim3(M_ / 16), dim3(192), 0, stream,
                       x, Wtb, Qb, Kb, Vt);
    hipLaunchKernelGGL(attn_kernel, dim3(C_ / 32, B_, KSPLIT), dim3(256), 0, stream,
                       Qb, Kb, Vt, adj, Opart, lpart);
    hipLaunchKernelGGL(combine_kernel, dim3(B_ * H_ * C_ * 8 / 256), dim3(256), 0, stream,
                       Opart, lpart, AOb);
    hipLaunchKernelGGL(out_proj_kernel, dim3(M_ / 32), dim3(256), 0, stream,
                       AOb, Wtb, bo, out);
}

// Round 8
// 386.687 us; speedup vs baseline: 1.5653x; 1.0571x over previous
//
#include <hip/hip_runtime.h>
#include <hip/hip_bf16.h>

// Problem constants (GATLayer): B=8, C=2048, IN=OUT=128, H=4, D=32
constexpr int B_  = 8;
constexpr int C_  = 2048;
constexpr int IND = 128;
constexpr int H_  = 4;
constexpr int D_  = 32;
constexpr int M_  = B_ * C_;          // 16384 tokens
constexpr float QSCALE = 0.17677669529663687f;   // 1/sqrt(32)
constexpr float L2E    = 1.4426950408889634f;
constexpr float QL2    = QSCALE * L2E;           // folded into Wt Q-rows

constexpr int KSPLIT = 4;             // global split (Opart = 33.6 MB, ws fits)
constexpr int KPG = C_ / KSPLIT;      // 512 keys per (block, kz)

typedef __attribute__((ext_vector_type(8))) short short8;
typedef __attribute__((ext_vector_type(4))) short s4t;
typedef __attribute__((ext_vector_type(4))) float f4t;
typedef __attribute__((ext_vector_type(4))) unsigned short us4;

// Device pass has these; host pass doesn't advertise via __has_builtin.
#if __has_builtin(__builtin_amdgcn_mfma_f32_16x16x16bf16_1k)
#define MFMA16(a, b, c) __builtin_amdgcn_mfma_f32_16x16x16bf16_1k(a, b, c, 0, 0, 0)
#else
#define MFMA16(a, b, c) (c)   // host-pass placeholder
#endif
#define MFMA32(a, b, c) __builtin_amdgcn_mfma_f32_16x16x32_bf16(a, b, c, 0, 0, 0)

__device__ __forceinline__ unsigned short f2bf(float f) {
    union { float f; unsigned u; } v; v.f = f;
    unsigned u = v.u + 0x7fffu + ((v.u >> 16) & 1u);   // RNE
    return (unsigned short)(u >> 16);
}

__device__ __forceinline__ s4t pack4_bf16(float p0, float p1, float p2, float p3) {
#if __has_builtin(__builtin_amdgcn_cvt_pk_bf16_f32)
    auto a = __builtin_amdgcn_cvt_pk_bf16_f32(p0, p1);
    auto b = __builtin_amdgcn_cvt_pk_bf16_f32(p2, p3);
    unsigned u[2];
    __builtin_memcpy(&u[0], &a, 4);
    __builtin_memcpy(&u[1], &b, 4);
    s4t pp;
    __builtin_memcpy(&pp, u, 8);
    return pp;
#else
    s4t pp;
    pp[0] = (short)f2bf(p0); pp[1] = (short)f2bf(p1);
    pp[2] = (short)f2bf(p2); pp[3] = (short)f2bf(p3);
    return pp;
#endif
}

__device__ __forceinline__ short8 cvt8(float4 a, float4 b) {
    s4t x = pack4_bf16(a.x, a.y, a.z, a.w);
    s4t y = pack4_bf16(b.x, b.y, b.z, b.w);
    short8 r;
    r[0] = x[0]; r[1] = x[1]; r[2] = x[2]; r[3] = x[3];
    r[4] = y[0]; r[5] = y[1]; r[6] = y[2]; r[7] = y[3];
    return r;
}

// ---------------------------------------------------------------------------
// K0: weight prep. Wtb[512][128] bf16: row n = column n of the fused weight
// [Wq*QL2 | Wk | Wv | Wo].  LDS tile transpose, padded stride.
__global__ __launch_bounds__(256) void prep_w_kernel(
    const float* __restrict__ Wq, const float* __restrict__ Wk,
    const float* __restrict__ Wv, const float* __restrict__ Wo,
    unsigned short* __restrict__ Wtb)
{
    __shared__ unsigned short lds[16][130];
    const int t  = threadIdx.x;
    const int n0 = blockIdx.x * 16;          // 0..511 in steps of 16

    const float* src; int nb; float sc = 1.0f;
    if      (n0 < 128) { src = Wq; nb = n0;       sc = QL2; }
    else if (n0 < 256) { src = Wk; nb = n0 - 128; }
    else if (n0 < 384) { src = Wv; nb = n0 - 256; }
    else               { src = Wo; nb = n0 - 384; }

    const int nn = t & 15, kk = t >> 4;      // kk: 0..15
#pragma unroll
    for (int kb = 0; kb < 8; ++kb) {
        const int k = kb * 16 + kk;
        lds[nn][k] = f2bf(src[k * IND + nb + nn] * sc);
    }
    __syncthreads();
    const int k = t & 127, rr = t >> 7;      // rr: 0..1
#pragma unroll
    for (int it = 0; it < 8; ++it) {
        const int r = it * 2 + rr;
        Wtb[(size_t)(n0 + r) * IND + k] = lds[r][k];
    }
}

// ---------------------------------------------------------------------------
// K1: QKV projection via MFMA. Block = 192 = 3 waves (one per matrix);
// grid (M/16, 2): grid.y splits the 8 N-tiles into two halves -> 6144 waves.
// Q/K computed TRANSPOSED (coalesced 8B row stores); V computed normal ->
// lands directly in Vt[b][d][c] layout.
__global__ __launch_bounds__(192) void qkv_proj_kernel(
    const float* __restrict__ x, const unsigned short* __restrict__ Wtb,
    unsigned short* __restrict__ Qb, unsigned short* __restrict__ Kb,
    unsigned short* __restrict__ Vt)
{
    const int t = threadIdx.x;
    const int w = t >> 6;                // 0:Q 1:K 2:V
    const int l = t & 63;
    const int lo = l & 15, hi = l >> 4;
    const int tok0 = blockIdx.x * 16;
    const int b  = tok0 >> 11;
    const int cb = tok0 & 2047;
    const int tile0 = blockIdx.y * 4;

    // x fragments: lane holds x[tok0+lo][kc*32 + hi*8 .. +8] as bf16
    short8 xb[4];
    const float* xrow = x + (size_t)(tok0 + lo) * IND;
#pragma unroll
    for (int kc = 0; kc < 4; ++kc) {
        const float4 a = *(const float4*)(xrow + kc * 32 + hi * 8);
        const float4 c = *(const float4*)(xrow + kc * 32 + hi * 8 + 4);
        xb[kc] = cvt8(a, c);
    }

    const unsigned short* wbase = Wtb + (size_t)(w * 128) * IND;
#pragma unroll
    for (int tile = 0; tile < 4; ++tile) {
        const int n0 = (tile0 + tile) * 16;
        short8 wf[4];
#pragma unroll
        for (int kc = 0; kc < 4; ++kc)
            wf[kc] = *(const short8*)(wbase + (size_t)(n0 + lo) * IND +
                                      kc * 32 + hi * 8);
        f4t acc = 0.f;
        if (w < 2) {
            // Yt = Wt-rows x x-rows: lane owns token=lo, cols n0+hi*4+r
#pragma unroll
            for (int kc = 0; kc < 4; ++kc) acc = MFMA32(wf[kc], xb[kc], acc);
            us4 v;
#pragma unroll
            for (int r = 0; r < 4; ++r) v[r] = f2bf(acc[r]);
            unsigned short* O = (w == 0) ? Qb : Kb;
            *(us4*)(O + (size_t)(tok0 + lo) * IND + n0 + hi * 4) = v;
        } else {
            // Y = x-rows x W-cols: lane owns d=n0+lo, tokens cb+hi*4+r
#pragma unroll
            for (int kc = 0; kc < 4; ++kc) acc = MFMA32(xb[kc], wf[kc], acc);
            us4 v;
#pragma unroll
            for (int r = 0; r < 4; ++r) v[r] = f2bf(acc[r]);
            *(us4*)(Vt + ((size_t)(b * IND) + n0 + lo) * C_ + cb + hi * 4) = v;
        }
    }
}

// ---------------------------------------------------------------------------
// K2: MFMA flash attention. Wave = 16 q x 4 heads x 512 keys (R3 shape,
// 4096 waves = 4/SIMD). Structural double-buffer: unroll-2 with two named
// register buffers for kf+adj (first-use / HBM-latency loads), one full
// stage of use-distance; vf (L3-resident, used late in stage) loads at
// stage top. launch_bounds(256,4) = 128-VGPR budget so the allocator
// keeps both stages live instead of collapsing the pipeline (R7 lesson:
// default squeezed to 52 VGPR and sank the prefetch).
__global__ __launch_bounds__(256, 4) void attn_kernel(
    const unsigned short* __restrict__ Qb, const unsigned short* __restrict__ Kb,
    const unsigned short* __restrict__ Vt, const float* __restrict__ adj,
    float* __restrict__ Opart, float* __restrict__ lpart)
{
    const int t  = threadIdx.x;
    const int s  = t >> 6;               // wave id = q-subtile (0..3)
    const int l  = t & 63;
    const int lo = l & 15, hi = l >> 4;
    const int b  = blockIdx.y;
    const int kz = blockIdx.z;
    const int q0 = blockIdx.x * 64;
    const int qs = q0 + s * 16 + lo;
    const int k0base = kz * KPG;
    const int NIT = KPG / 16;            // 32

    short8 qf[4];
#pragma unroll
    for (int h = 0; h < 4; ++h)
        qf[h] = *(const short8*)(Qb + ((size_t)(b * C_) + qs) * IND + h * 32 + hi * 8);

    f4t acc[4][2];
#pragma unroll
    for (int h = 0; h < 4; ++h) { acc[h][0] = 0.f; acc[h][1] = 0.f; }
    float ls[4] = {0.f, 0.f, 0.f, 0.f};

    const float* adjrow = adj + ((size_t)(b * C_) + qs) * C_ + hi * 4;
    const unsigned short* Krow = Kb + ((size_t)(b * C_) + lo) * IND + hi * 8;
    const unsigned short* Vrow = Vt + ((size_t)(b * IND) + lo) * C_ + hi * 4;

    auto loadKA = [&](int st, short8 kf[4], f4t& av) {
        const int k0 = k0base + st * 16;
#pragma unroll
        for (int h = 0; h < 4; ++h)
            kf[h] = *(const short8*)(Krow + (size_t)k0 * IND + h * 32);
        av = *(const f4t*)(adjrow + k0);
    };

    auto computeS = [&](const short8 kf[4], const f4t av, int st) {
        const int k0 = k0base + st * 16;
        s4t vf[8];
#pragma unroll
        for (int h = 0; h < 4; ++h) {
            vf[h * 2]     = *(const s4t*)(Vrow + (size_t)(h * 32) * C_ + k0);
            vf[h * 2 + 1] = *(const s4t*)(Vrow + (size_t)(h * 32 + 16) * C_ + k0);
        }
#pragma unroll
        for (int h = 0; h < 4; ++h) {
            f4t st4 = MFMA32(kf[h], qf[h], (f4t)0.f);
            float p[4];
#pragma unroll
            for (int r = 0; r < 4; ++r) {
                const float a = st4[r] * av[r];          // adj gate (pre-leaky)
                const float m = fmaxf(a, 0.2f * a);      // LeakyReLU(0.2)
                p[r] = exp2f(m);                         // e^s (L2E pre-folded)
                ls[h] += p[r];
            }
            const s4t pp = pack4_bf16(p[0], p[1], p[2], p[3]);
            acc[h][0] = MFMA16(pp, vf[h * 2], acc[h][0]);
            acc[h][1] = MFMA16(pp, vf[h * 2 + 1], acc[h][1]);
        }
    };

    short8 kfA[4], kfB[4];
    f4t avA, avB;
    loadKA(0, kfA, avA);
    for (int it = 0; it < NIT; it += 2) {
        loadKA(it + 1 < NIT ? it + 1 : it, kfB, avB);
        computeS(kfA, avA, it);
        loadKA(it + 2 < NIT ? it + 2 : NIT - 1, kfA, avA);
        computeS(kfB, avB, it + 1);
    }

    // reduce l over the 4 lane-groups (k quarters) within the wave
#pragma unroll
    for (int h = 0; h < 4; ++h) {
        ls[h] += __shfl_xor(ls[h], 16, 64);
        ls[h] += __shfl_xor(ls[h], 32, 64);
    }

    const size_t BHC   = (size_t)B_ * H_ * C_;
    const size_t obase = (size_t)kz * BHC;

    // each lane writes l for head=hi, q=qs
    const float lw = (hi == 0) ? ls[0] : (hi == 1) ? ls[1] : (hi == 2) ? ls[2] : ls[3];
    lpart[obase + (size_t)(b * H_ + hi) * C_ + qs] = lw;

    // O: PV C-layout: lane owns q = q0+s*16+hi*4+r, d = h*32+dh*16+lo
#pragma unroll
    for (int h = 0; h < 4; ++h) {
        const size_t rb = obase + (size_t)(b * H_ + h) * C_ + q0 + s * 16 + hi * 4;
#pragma unroll
        for (int dh = 0; dh < 2; ++dh)
#pragma unroll
            for (int r = 0; r < 4; ++r)
                Opart[(rb + r) * D_ + dh * 16 + lo] = acc[h][dh][r];
    }
}

// ---------------------------------------------------------------------------
// K3: combine split-K partials -> AOb (bf16):  AOb = (sum O_kz)/(sum l_kz)
__global__ __launch_bounds__(256) void combine_kernel(
    const float* __restrict__ Opart, const float* __restrict__ lpart,
    unsigned short* __restrict__ AOb)
{
    const int cid = blockIdx.x * 256 + threadIdx.x;   // 0 .. 524287
    const int j   = cid & 7;                          // float4 chunk of D=32
    const int idx = cid >> 3;                         // (b*H+h)*C + q
    const int q  = idx & (C_ - 1);
    const int bh = idx >> 11;
    const int h  = bh & (H_ - 1);
    const int b  = bh >> 2;
    const size_t BHC = (size_t)B_ * H_ * C_;

    float4 acc = {0.f, 0.f, 0.f, 0.f};
    float lsum = 0.f;
#pragma unroll
    for (int kz = 0; kz < KSPLIT; ++kz) {
        const size_t base = (size_t)kz * BHC + idx;
        lsum += lpart[base];
        const float4 v = *(const float4*)(Opart + base * D_ + j * 4);
        acc.x += v.x; acc.y += v.y; acc.z += v.z; acc.w += v.w;
    }
    const float inv = 1.f / lsum;
    us4 o;
    o[0] = f2bf(acc.x * inv); o[1] = f2bf(acc.y * inv);
    o[2] = f2bf(acc.z * inv); o[3] = f2bf(acc.w * inv);
    *(us4*)(AOb + ((size_t)(b * C_) + q) * IND + h * D_ + j * 4) = o;
}

// ---------------------------------------------------------------------------
// K4: output projection via MFMA (transposed-compute -> coalesced float4
// stores with fused bias). Block = 256 = 4 waves = 4 N-quarters; 16 tokens
// per block, grid 1024 -> 4096 waves.
__global__ __launch_bounds__(256) void out_proj_kernel(
    const unsigned short* __restrict__ AOb, const unsigned short* __restrict__ Wtb,
    const float* __restrict__ bo, float* __restrict__ out)
{
    const int t  = threadIdx.x;
    const int w  = t >> 6;               // N-quarter
    const int l  = t & 63;
    const int lo = l & 15, hi = l >> 4;
    const int tok0 = blockIdx.x * 16;

    short8 af[4];
    const unsigned short* arow = AOb + (size_t)(tok0 + lo) * IND;
#pragma unroll
    for (int kc = 0; kc < 4; ++kc)
        af[kc] = *(const short8*)(arow + kc * 32 + hi * 8);

    const unsigned short* wbase = Wtb + (size_t)384 * IND;
#pragma unroll
    for (int tt = 0; tt < 2; ++tt) {
        const int n0 = w * 32 + tt * 16;
        short8 wf[4];
#pragma unroll
        for (int kc = 0; kc < 4; ++kc)
            wf[kc] = *(const short8*)(wbase + (size_t)(n0 + lo) * IND +
                                      kc * 32 + hi * 8);
        f4t acc = 0.f;
#pragma unroll
        for (int kc = 0; kc < 4; ++kc) acc = MFMA32(wf[kc], af[kc], acc);
        const f4t bv = *(const f4t*)(bo + n0 + hi * 4);
        float4 o;
        o.x = acc[0] + bv[0]; o.y = acc[1] + bv[1];
        o.z = acc[2] + bv[2]; o.w = acc[3] + bv[3];
        *(float4*)(out + (size_t)(tok0 + lo) * IND + n0 + hi * 4) = o;
    }
}

// ---------------------------------------------------------------------------
extern "C" void kernel_launch(void* const* d_in, const int* in_sizes, int n_in,
                              void* d_out, int out_size, void* d_ws, size_t ws_size,
                              hipStream_t stream) {
    const float* x   = (const float*)d_in[0];
    const float* adj = (const float*)d_in[1];
    const float* Wq  = (const float*)d_in[2];
    const float* Wk  = (const float*)d_in[3];
    const float* Wv  = (const float*)d_in[4];
    const float* Wo  = (const float*)d_in[5];
    const float* bo  = (const float*)d_in[6];
    float* out = (float*)d_out;

    // workspace (bf16 unless noted): Wtb 128KB; Qb/Kb/Vt 4.2MB each;
    // AOb 4.2MB; Opart fp32 33.6MB; lpart fp32 1MB  -> ~47.5 MB total
    unsigned short* Wtb = (unsigned short*)d_ws;
    unsigned short* Qb  = Wtb + (size_t)512 * IND;
    unsigned short* Kb  = Qb + (size_t)M_ * IND;
    unsigned short* Vt  = Kb + (size_t)M_ * IND;
    unsigned short* AOb = Vt + (size_t)M_ * IND;
    float* Opart = (float*)(AOb + (size_t)M_ * IND);
    float* lpart = Opart + (size_t)KSPLIT * B_ * H_ * C_ * D_;

    hipLaunchKernelGGL(prep_w_kernel, dim3(32), dim3(256), 0, stream,
                       Wq, Wk, Wv, Wo, Wtb);
    hipLaunchKernelGGL(qkv_proj_kernel, dim3(M_ / 16, 2), dim3(192), 0, stream,
                       x, Wtb, Qb, Kb, Vt);
    hipLaunchKernelGGL(attn_kernel, dim3(C_ / 64, B_, KSPLIT), dim3(256), 0, stream,
                       Qb, Kb, Vt, adj, Opart, lpart);
    hipLaunchKernelGGL(combine_kernel, dim3(B_ * H_ * C_ * 8 / 256), dim3(256), 0, stream,
                       Opart, lpart, AOb);
    hipLaunchKernelGGL(out_proj_kernel, dim3(M_ / 16), dim3(256), 0, stream,
                       AOb, Wtb, bo, out);
}